// Round 5
// baseline (331.779 us; speedup 1.0000x reference)
//
#include <hip/hip_runtime.h>
#include <hip/hip_bf16.h>

typedef __attribute__((ext_vector_type(8))) short short8;
typedef __attribute__((ext_vector_type(4))) short short4v;
typedef __attribute__((ext_vector_type(4))) float f32x4;
typedef __hip_bfloat16 bf16;

#define SEQ 2048
#define DIM 2048
#define NH 32
#define NKV 8
#define HD 64
#define QKVD 3072
#define KVD 512
#define SMSCALE 0.18033688011112042f  /* 0.125 * log2(e), folded into Q at rope time */

__device__ inline void gld_lds16(const bf16* g, bf16* l) {
    __builtin_amdgcn_global_load_lds((const __attribute__((address_space(1))) void*)g,
                                     (__attribute__((address_space(3))) void*)l, 16, 0, 0);
}

__device__ inline void store_val(float* p, float v) { *p = v; }
__device__ inline void store_val(bf16* p, float v) { *p = __float2bfloat16(v); }

__device__ inline unsigned pkbf16(float a, float b) {
    __hip_bfloat162 h = __float22bfloat162_rn(make_float2(a, b));
    return *(unsigned*)&h;
}

__device__ inline float b2f(short x) {
    unsigned u = (unsigned)(unsigned short)x << 16;
    union { unsigned u; float f; } c; c.u = u; return c.f;
}

// ---------------- fused fp32 -> bf16 convert for x | wqkv | wo ----------------
__global__ void cvt3_kernel(const float* __restrict__ x, const float* __restrict__ wqkv,
                            const float* __restrict__ wo, bf16* __restrict__ out) {
    int i = blockIdx.x * blockDim.x + threadIdx.x;
    const float* src; int off;
    if (i < 2097152) { src = x; off = i; }
    else if (i < 3670016) { src = wqkv; off = i - 2097152; }
    else { src = wo; off = i - 3670016; }
    float4 v = ((const float4*)src)[off];
    uint2 u;
    u.x = pkbf16(v.x, v.y);
    u.y = pkbf16(v.z, v.w);
    ((uint2*)out)[i] = u;
}

// ---------------- NT GEMM: C[M,N] = A[M,K] * Bt[N,K]^T  (m97 structure) ----------------
// Used for wo (M=4096,N=2048): grid 16x32 = 512 blocks = 2/CU, 100% chip fill.
template <typename CT>
__global__ __launch_bounds__(256, 3) void gemm_nt(const bf16* __restrict__ A,
                                                  const bf16* __restrict__ Bt,
                                                  CT* __restrict__ C,
                                                  int M, int N, int K) {
    __shared__ bf16 As[128 * 32];
    __shared__ bf16 Bs[128 * 32];
    const int tid = threadIdx.x;
    const int lane = tid & 63;
    const int quad = lane >> 4;
    const int r16 = lane & 15;
    const int wave = tid >> 6;
    const int bm = blockIdx.y * 128;
    const int bn = blockIdx.x * 128;
    const int wm = (wave >> 1) * 64;
    const int wn = (wave & 1) * 64;

    f32x4 acc[4][4] = {};

    const int arow = tid >> 2;
    const int kch = (tid & 3) * 8;
    const bf16* Ap = A + (size_t)(bm + arow) * K + kch;
    const bf16* Bp = Bt + (size_t)(bn + arow) * K + kch;
    bf16* Asd = As + tid * 8;
    bf16* Bsd = Bs + tid * 8;
    const int kq = quad * 8;

    for (int k0 = 0; k0 < K; k0 += 32) {
        __syncthreads();
        gld_lds16(Ap, Asd);
        gld_lds16(Ap + (size_t)64 * K, Asd + 64 * 32);
        gld_lds16(Bp, Bsd);
        gld_lds16(Bp + (size_t)64 * K, Bsd + 64 * 32);
        Ap += 32; Bp += 32;
        __syncthreads();
        short8 af[4], bfr[4];
#pragma unroll
        for (int i = 0; i < 4; i++)
            af[i] = *(const short8*)(As + (wm + i * 16 + r16) * 32 + kq);
#pragma unroll
        for (int j = 0; j < 4; j++)
            bfr[j] = *(const short8*)(Bs + (wn + j * 16 + r16) * 32 + kq);
#pragma unroll
        for (int i = 0; i < 4; i++)
#pragma unroll
            for (int j = 0; j < 4; j++)
                acc[i][j] = __builtin_amdgcn_mfma_f32_16x16x32_bf16(af[i], bfr[j], acc[i][j], 0, 0, 0);
    }
#pragma unroll
    for (int i = 0; i < 4; i++)
#pragma unroll
        for (int j = 0; j < 4; j++) {
            int row = bm + wm + i * 16 + quad * 4;
            int col = bn + wn + j * 16 + r16;
#pragma unroll
            for (int r = 0; r < 4; r++)
                store_val(C + (size_t)(row + r) * N + col, acc[i][j][r]);
        }
}

// ---------------- 8-phase 256x256 NT GEMM v2: reads AFTER the wait ----------------
// Fix vs R3: phase = {stage -> vmcnt(6) -> barrier -> sched_barrier -> ds_read -> MFMA}.
// Stage order A0,B0,B1,A1 (ph1..ph4); compute order Q00(af,bf0), Q01(af,bf1),
// Q11(af2,bf1), Q10(af2,bf0). FIFO trace: every half-tile gets a 3-4 phase
// (~600-800cyc) in-flight window before its vmcnt(6) forces it; 3 vmcnt + 4
// barriers per K-tile (R3: 4+8); ph4 is register-only (no wait, no barrier).
// Long-lived operand is bf0 (16 VGPR) not af (32) -> peak ~210 VGPR, no spill.
// ph3-end barrier is the read-fence: all reads of buf[bi] done before any wave
// issues next-tile ph1's stage into buf[bi]. Last tile peeled with waits 4/2/0.
// sched_barrier(0) after each s_barrier: the builtin has no memory semantics,
// without it the compiler may hoist ds_read/gld_lds across the barrier.
template <typename CT>
__global__ __launch_bounds__(512, 2) void gemm8p(const bf16* __restrict__ A,
                                                 const bf16* __restrict__ Bt,
                                                 CT* __restrict__ C,
                                                 int N, int K) {
    __shared__ bf16 Abuf[2][16384];
    __shared__ bf16 Bbuf[2][16384];
    const int tid = threadIdx.x;
    const int lane = tid & 63;
    const int quad = lane >> 4;
    const int r16 = lane & 15;
    const int wv = tid >> 6;
    const int wm = wv >> 2;        // 0..1
    const int wn = wv & 3;         // 0..3
    const int bm = blockIdx.y * 256;
    const int bn = blockIdx.x * 256;
    const int swz = (lane & 7) * 8;

    const int sc = (((tid & 7) ^ ((tid >> 3) & 7)) * 8);
    const bf16* Ap = A + (size_t)(bm + (tid >> 3)) * K + sc;
    const bf16* Bp = Bt + (size_t)(bn + (tid >> 3)) * K + sc;

    f32x4 acc[8][4] = {};
    const int NT = K >> 6;

    // prologue: tile0 staged in FIFO order A0, B0, B1, A1 (matches wait schedule)
    {
        bf16* Ad = &Abuf[0][0] + tid * 8;
        bf16* Bd = &Bbuf[0][0] + tid * 8;
        gld_lds16(Ap, Ad);                          gld_lds16(Ap + (size_t)64 * K, Ad + 4096);
        gld_lds16(Bp, Bd);                          gld_lds16(Bp + (size_t)64 * K, Bd + 4096);
        gld_lds16(Bp + (size_t)128 * K, Bd + 8192); gld_lds16(Bp + (size_t)192 * K, Bd + 12288);
        gld_lds16(Ap + (size_t)128 * K, Ad + 8192); gld_lds16(Ap + (size_t)192 * K, Ad + 12288);
    }

    short8 af[4][2], af2[4][2], bf0[2][2], bf1[2][2];

#define VMW(nstr) asm volatile("s_waitcnt vmcnt(" nstr ")" ::: "memory")
#define BARF() { __builtin_amdgcn_s_barrier(); __builtin_amdgcn_sched_barrier(0); }
#define RD_AF(dst, rbase)                                                     \
    _Pragma("unroll")                                                         \
    for (int i = 0; i < 4; i++) {                                             \
        const bf16* p = Ac + ((rbase) + wm * 64 + i * 16 + r16) * 64;         \
        dst[i][0] = *(const short8*)(p + ((quad * 8) ^ swz));                 \
        dst[i][1] = *(const short8*)(p + ((32 + quad * 8) ^ swz));            \
    }
#define RD_BF(dst, rbase)                                                     \
    _Pragma("unroll")                                                         \
    for (int j = 0; j < 2; j++) {                                             \
        const bf16* p = Bc + ((rbase) + wn * 32 + j * 16 + r16) * 64;         \
        dst[j][0] = *(const short8*)(p + ((quad * 8) ^ swz));                 \
        dst[j][1] = *(const short8*)(p + ((32 + quad * 8) ^ swz));            \
    }
#define MFMA_BF16(a, b, c) __builtin_amdgcn_mfma_f32_16x16x32_bf16(a, b, c, 0, 0, 0)
#define MFMAQ(ai, bj, io, jo)                                                 \
    __builtin_amdgcn_s_setprio(1);                                            \
    _Pragma("unroll")                                                         \
    for (int i = 0; i < 4; i++)                                               \
        _Pragma("unroll")                                                     \
        for (int j = 0; j < 2; j++) {                                         \
            acc[(io) + i][(jo) + j] = MFMA_BF16(ai[i][0], bj[j][0], acc[(io) + i][(jo) + j]); \
            acc[(io) + i][(jo) + j] = MFMA_BF16(ai[i][1], bj[j][1], acc[(io) + i][(jo) + j]); \
        }                                                                     \
    __builtin_amdgcn_s_setprio(0);

#pragma unroll 1
    for (int t = 0; t < NT - 1; t++) {
        const int bi = t & 1;
        const bf16* Ac = &Abuf[bi][0];
        const bf16* Bc = &Bbuf[bi][0];
        bf16* Ad = &Abuf[bi ^ 1][0] + tid * 8;
        bf16* Bd = &Bbuf[bi ^ 1][0] + tid * 8;
        const bf16* Apn = Ap + (size_t)(t + 1) * 64;
        const bf16* Bpn = Bp + (size_t)(t + 1) * 64;

        // ph1: stage A0'; wait(6) [forces A0,B0 of t]; read af,bf0; Q00
        gld_lds16(Apn, Ad); gld_lds16(Apn + (size_t)64 * K, Ad + 4096);
        VMW("6");
        BARF();
        RD_AF(af, 0)
        RD_BF(bf0, 0)
        MFMAQ(af, bf0, 0, 0)

        // ph2: stage B0'; wait(6) [forces B1 of t]; read bf1; Q01
        gld_lds16(Bpn, Bd); gld_lds16(Bpn + (size_t)64 * K, Bd + 4096);
        VMW("6");
        BARF();
        RD_BF(bf1, 128)
        MFMAQ(af, bf1, 0, 2)

        // ph3: stage B1'; wait(6) [forces A1 of t]; read af2; Q11; read-fence
        gld_lds16(Bpn + (size_t)128 * K, Bd + 8192); gld_lds16(Bpn + (size_t)192 * K, Bd + 12288);
        VMW("6");
        BARF();
        RD_AF(af2, 128)
        MFMAQ(af2, bf1, 4, 2)
        BARF();   // all reads of buf[bi] complete before next tile stages into it

        // ph4: stage A1'; Q10 (registers only -- no wait, no barrier)
        gld_lds16(Apn + (size_t)128 * K, Ad + 8192); gld_lds16(Apn + (size_t)192 * K, Ad + 12288);
        MFMAQ(af2, bf0, 4, 0)
    }

    // peeled last tile: no staging, draining waits 4 / 2 / 0
    {
        const int bi = (NT - 1) & 1;
        const bf16* Ac = &Abuf[bi][0];
        const bf16* Bc = &Bbuf[bi][0];
        VMW("4");
        BARF();
        RD_AF(af, 0)
        RD_BF(bf0, 0)
        MFMAQ(af, bf0, 0, 0)
        VMW("2");
        BARF();
        RD_BF(bf1, 128)
        MFMAQ(af, bf1, 0, 2)
        VMW("0");
        BARF();
        RD_AF(af2, 128)
        MFMAQ(af2, bf1, 4, 2)
        MFMAQ(af2, bf0, 4, 0)
    }

    // epilogue: C-write (layout verified in R3/R4 runs)
#pragma unroll
    for (int i = 0; i < 8; i++) {
        int row = bm + (i < 4 ? wm * 64 + i * 16 : 128 + wm * 64 + (i - 4) * 16) + quad * 4;
#pragma unroll
        for (int j = 0; j < 4; j++) {
            int col = bn + wn * 32 + (j < 2 ? j * 16 : 128 + (j - 2) * 16) + r16;
#pragma unroll
            for (int r = 0; r < 4; r++)
                store_val(C + (size_t)(row + r) * N + col, acc[i][j][r]);
        }
    }
#undef VMW
#undef BARF
#undef RD_AF
#undef RD_BF
#undef MFMA_BF16
#undef MFMAQ
}

// ---------------- RoPE on Q,K, vectorized x8 (Q pre-scaled by SMSCALE) ----------------
__global__ void rope_qk_kernel(const bf16* __restrict__ qkv, const float* __restrict__ fc,
                               bf16* __restrict__ qr, bf16* __restrict__ kr) {
    const int row = blockIdx.y;
    const int s = row & (SEQ - 1);
    const int col = (blockIdx.x * 64 + threadIdx.x) * 8;  // 0..2552, step 8
    const bf16* src = qkv + (size_t)row * QKVD + col;
    short8 v = *(const short8*)src;
    const int j0 = (col & 63) >> 1;
    const float4* fcp = (const float4*)(fc + ((size_t)s * 32 + j0) * 2);
    float4 f01 = fcp[0];
    float4 f23 = fcp[1];

    bf16* dst;
    float sc;
    if (col < DIM) { dst = qr + (size_t)row * DIM + col; sc = SMSCALE; }
    else           { dst = kr + (size_t)row * KVD + (col - DIM); sc = 1.0f; }

    float x0 = b2f(v[0]), x1 = b2f(v[1]), x2 = b2f(v[2]), x3 = b2f(v[3]);
    float x4 = b2f(v[4]), x5 = b2f(v[5]), x6 = b2f(v[6]), x7 = b2f(v[7]);
    float c0 = f01.x * sc, s0 = f01.y * sc, c1 = f01.z * sc, s1 = f01.w * sc;
    float c2 = f23.x * sc, s2 = f23.y * sc, c3 = f23.z * sc, s3 = f23.w * sc;

    uint4 o;
    o.x = pkbf16(x0 * c0 - x1 * s0, x1 * c0 + x0 * s0);
    o.y = pkbf16(x2 * c1 - x3 * s1, x3 * c1 + x2 * s1);
    o.z = pkbf16(x4 * c2 - x5 * s2, x5 * c2 + x4 * s2);
    o.w = pkbf16(x6 * c3 - x7 * s3, x7 * c3 + x6 * s3);
    *(uint4*)dst = o;
}

// ---------------- V transpose: qkv[s][2560+kvh*64+d] -> vt[(b,kvh,d)][s] ----------------
__global__ void rope_v_kernel(const bf16* __restrict__ qkv, bf16* __restrict__ vt) {
    const int t = threadIdx.x;
    const int so = t & 63;
    const int dq = t >> 6;
    const int bk = blockIdx.y;
    const int s = blockIdx.x * 64 + so;
    const int b = bk >> 3;
    const bf16* src = qkv + ((size_t)b * SEQ + s) * QKVD + DIM + KVD + (bk & 7) * HD + dq * 16;
    short8 v0 = *(const short8*)src;
    short8 v1 = *(const short8*)(src + 8);
    short* dst = (short*)(vt + ((size_t)bk * HD + dq * 16) * SEQ + s);
#pragma unroll
    for (int j = 0; j < 8; j++) dst[(size_t)j * SEQ] = v0[j];
#pragma unroll
    for (int j = 0; j < 8; j++) dst[(size_t)(8 + j) * SEQ] = v1[j];
}

// ---------------- Flash attention (frozen: 93 us verified, counters stable) ----------------
__global__ __launch_bounds__(256, 4) void attn_kernel(const bf16* __restrict__ qr,
                                                      const bf16* __restrict__ kr,
                                                      const bf16* __restrict__ vt,
                                                      bf16* __restrict__ out) {
    __shared__ bf16 Ks[8192];
    __shared__ bf16 Vs[8192];
    const int t = threadIdx.x;
    const int lane = t & 63;
    const int wv = t >> 6;
    const int quad = lane >> 4;
    const int r16 = lane & 15;

    const int wg = blockIdx.x;
    const int xcd = wg & 7;
    const int kk = wg >> 3;
    const int bk = xcd * 2 + (kk & 1);
    const int qt = 127 - (kk >> 1);
    const int b = bk >> 3;
    const int kvh = bk & 7;
    const int h = kvh * 4 + wv;
    const int q0 = qt * 16;
    const int nkb = (qt >> 2) + 1;

    const bf16* Kg = kr + ((size_t)b * SEQ + lane) * KVD + kvh * HD + wv * 8;
    const bf16* Vg = vt + ((size_t)(b * NKV + kvh) * HD + lane) * SEQ + wv * 8;

    const char* kl = (const char*)Ks + quad * 1024 + r16 * 16;
    const char* vl = (const char*)Vs + (quad >> 1) * 1024 + r16 * 16 + (quad & 1) * 8;

    union PB { short4v s; unsigned u[2]; };

    const short one_bf16 = (short)0x3F80;
    const short4v ones = {one_bf16, one_bf16, one_bf16, one_bf16};

    const bf16* Qp = qr + ((size_t)b * SEQ + q0 + r16) * DIM + h * HD + quad * 8;
    short8 qa0 = *(const short8*)(Qp);
    short8 qa1 = *(const short8*)(Qp + 32);

    f32x4 o[4] = {};
    f32x4 o_l = {};

    {
        bf16* Ksd = Ks + t * 8;
        bf16* Vsd = Vs + t * 8;
        gld_lds16(Kg, Ksd);      gld_lds16(Kg + 32, Ksd + 2048);
        gld_lds16(Vg, Vsd);      gld_lds16(Vg + 32, Vsd + 2048);
    }

    for (int kb = 0; kb < nkb; kb++) {
        __syncthreads();
        const int buf = kb & 1;
        if (kb + 1 < nkb) {
            const bf16* Kgn = Kg + (size_t)(kb + 1) * 64 * KVD;
            const bf16* Vgn = Vg + (kb + 1) * 64;
            bf16* Ksd = Ks + (buf ^ 1) * 4096 + t * 8;
            bf16* Vsd = Vs + (buf ^ 1) * 4096 + t * 8;
            gld_lds16(Kgn, Ksd);      gld_lds16(Kgn + 32, Ksd + 2048);
            gld_lds16(Vgn, Vsd);      gld_lds16(Vgn + 32, Vsd + 2048);
        }
        const char* klb = kl + buf * 8192;
        const char* vlb = vl + buf * 8192;

        const f32x4 z = {0.f, 0.f, 0.f, 0.f};
        f32x4 st[4];
        __builtin_amdgcn_s_setprio(1);
#pragma unroll
        for (int n = 0; n < 4; n++) {
            short8 kf0 = *(const short8*)(klb + n * 256);
            short8 kf1 = *(const short8*)(klb + 4096 + n * 256);
            st[n] = __builtin_amdgcn_mfma_f32_16x16x32_bf16(kf0, qa0, z, 0, 0, 0);
            st[n] = __builtin_amdgcn_mfma_f32_16x16x32_bf16(kf1, qa1, st[n], 0, 0, 0);
        }
        __builtin_amdgcn_s_setprio(0);

        short4v vf[4][4];
#pragma unroll
        for (int dt = 0; dt < 4; dt++)
#pragma unroll
            for (int n = 0; n < 4; n++)
                vf[dt][n] = *(const short4v*)(vlb + n * 2048 + dt * 256);
        __builtin_amdgcn_sched_barrier(0);

        if (kb == nkb - 1) {
            const int kbase = kb * 64;
#pragma unroll
            for (int n = 0; n < 4; n++)
#pragma unroll
                for (int r = 0; r < 4; r++) {
                    int key = kbase + n * 16 + quad * 4 + r;
                    if (key > q0 + r16) st[n][r] = -__builtin_inff();
                }
        }

        PB pbs[4];
#pragma unroll
        for (int n = 0; n < 4; n++) {
            float p0 = exp2f(st[n][0]);
            float p1 = exp2f(st[n][1]);
            float p2 = exp2f(st[n][2]);
            float p3 = exp2f(st[n][3]);
            pbs[n].u[0] = pkbf16(p0, p1);
            pbs[n].u[1] = pkbf16(p2, p3);
        }

        __builtin_amdgcn_s_setprio(1);
#pragma unroll
        for (int dt = 0; dt < 4; dt++)
#pragma unroll
            for (int n = 0; n < 4; n++)
                o[dt] = __builtin_amdgcn_mfma_f32_16x16x16bf16_1k(vf[dt][n], pbs[n].s, o[dt], 0, 0, 0);
#pragma unroll
        for (int n = 0; n < 4; n++)
            o_l = __builtin_amdgcn_mfma_f32_16x16x16bf16_1k(ones, pbs[n].s, o_l, 0, 0, 0);
        __builtin_amdgcn_s_setprio(0);
    }

    float inv_l = 1.f / o_l[0];
    bf16* Op = out + ((size_t)b * SEQ + q0 + r16) * DIM + h * HD + quad * 4;
#pragma unroll
    for (int dt = 0; dt < 4; dt++) {
        PB pk;
        pk.u[0] = pkbf16(o[dt][0] * inv_l, o[dt][1] * inv_l);
        pk.u[1] = pkbf16(o[dt][2] * inv_l, o[dt][3] * inv_l);
        *(short4v*)(Op + dt * 16) = pk.s;
    }
}

extern "C" void kernel_launch(void* const* d_in, const int* in_sizes, int n_in,
                              void* d_out, int out_size, void* d_ws, size_t ws_size,
                              hipStream_t stream) {
    (void)in_sizes; (void)n_in; (void)out_size; (void)ws_size;
    const float* x    = (const float*)d_in[0];
    const float* fc   = (const float*)d_in[1];
    const float* wqkv = (const float*)d_in[3];
    const float* wo   = (const float*)d_in[4];
    float* out = (float*)d_out;

    char* w = (char*)d_ws;
    bf16* xb    = (bf16*)(w);
    bf16* wqkvb = (bf16*)(w + 16777216);
    bf16* wob   = (bf16*)(w + 29360128);
    bf16* qkvb  = (bf16*)(w + 37748736);
    bf16* kr    = (bf16*)(w + 62914560);
    bf16* vt    = (bf16*)(w + 67108864);
    bf16* qr = xb;
    bf16* attnb = qkvb;

    cvt3_kernel<<<18432, 256, 0, stream>>>(x, wqkv, wo, xb);
    gemm8p<bf16><<<dim3(12, 16), 512, 0, stream>>>(xb, wqkvb, qkvb, QKVD, DIM);   // v2 schedule
    rope_qk_kernel<<<dim3(5, 4096), 64, 0, stream>>>(qkvb, fc, qr, kr);
    rope_v_kernel<<<dim3(32, 16), 256, 0, stream>>>(qkvb, vt);
    attn_kernel<<<dim3(2048), 256, 0, stream>>>(qr, kr, vt, attnb);
    gemm_nt<float><<<dim3(16, 32), 256, 0, stream>>>(attnb, wob, out, 4096, DIM, DIM);
}

// Round 6
// 326.243 us; speedup vs baseline: 1.0170x; 1.0170x over previous
//
#include <hip/hip_runtime.h>
#include <hip/hip_bf16.h>

typedef __attribute__((ext_vector_type(8))) short short8;
typedef __attribute__((ext_vector_type(4))) short short4v;
typedef __attribute__((ext_vector_type(4))) float f32x4;
typedef __hip_bfloat16 bf16;

#define SEQ 2048
#define DIM 2048
#define NH 32
#define NKV 8
#define HD 64
#define QKVD 3072
#define KVD 512
#define SMSCALE 0.18033688011112042f  /* 0.125 * log2(e), folded into Q at rope time */

__device__ inline void gld_lds16(const bf16* g, bf16* l) {
    __builtin_amdgcn_global_load_lds((const __attribute__((address_space(1))) void*)g,
                                     (__attribute__((address_space(3))) void*)l, 16, 0, 0);
}

__device__ inline void store_val(float* p, float v) { *p = v; }
__device__ inline void store_val(bf16* p, float v) { *p = __float2bfloat16(v); }

__device__ inline unsigned pkbf16(float a, float b) {
    __hip_bfloat162 h = __float22bfloat162_rn(make_float2(a, b));
    return *(unsigned*)&h;
}

__device__ inline float b2f(short x) {
    unsigned u = (unsigned)(unsigned short)x << 16;
    union { unsigned u; float f; } c; c.u = u; return c.f;
}

// ---------------- fused fp32 -> bf16 convert for x | wqkv | wo ----------------
__global__ void cvt3_kernel(const float* __restrict__ x, const float* __restrict__ wqkv,
                            const float* __restrict__ wo, bf16* __restrict__ out) {
    int i = blockIdx.x * blockDim.x + threadIdx.x;
    const float* src; int off;
    if (i < 2097152) { src = x; off = i; }
    else if (i < 3670016) { src = wqkv; off = i - 2097152; }
    else { src = wo; off = i - 3670016; }
    float4 v = ((const float4*)src)[off];
    uint2 u;
    u.x = pkbf16(v.x, v.y);
    u.y = pkbf16(v.z, v.w);
    ((uint2*)out)[i] = u;
}

// ---------------- NT GEMM: C[M,N] = A[M,K] * Bt[N,K]^T  (m97 structure, verified) ----------------
template <typename CT>
__global__ __launch_bounds__(256, 3) void gemm_nt(const bf16* __restrict__ A,
                                                  const bf16* __restrict__ Bt,
                                                  CT* __restrict__ C,
                                                  int M, int N, int K) {
    __shared__ bf16 As[128 * 32];
    __shared__ bf16 Bs[128 * 32];
    const int tid = threadIdx.x;
    const int lane = tid & 63;
    const int quad = lane >> 4;
    const int r16 = lane & 15;
    const int wave = tid >> 6;
    const int bm = blockIdx.y * 128;
    const int bn = blockIdx.x * 128;
    const int wm = (wave >> 1) * 64;
    const int wn = (wave & 1) * 64;

    f32x4 acc[4][4] = {};

    const int arow = tid >> 2;
    const int kch = (tid & 3) * 8;
    const bf16* Ap = A + (size_t)(bm + arow) * K + kch;
    const bf16* Bp = Bt + (size_t)(bn + arow) * K + kch;
    bf16* Asd = As + tid * 8;
    bf16* Bsd = Bs + tid * 8;
    const int kq = quad * 8;

    for (int k0 = 0; k0 < K; k0 += 32) {
        __syncthreads();
        gld_lds16(Ap, Asd);
        gld_lds16(Ap + (size_t)64 * K, Asd + 64 * 32);
        gld_lds16(Bp, Bsd);
        gld_lds16(Bp + (size_t)64 * K, Bsd + 64 * 32);
        Ap += 32; Bp += 32;
        __syncthreads();
        short8 af[4], bfr[4];
#pragma unroll
        for (int i = 0; i < 4; i++)
            af[i] = *(const short8*)(As + (wm + i * 16 + r16) * 32 + kq);
#pragma unroll
        for (int j = 0; j < 4; j++)
            bfr[j] = *(const short8*)(Bs + (wn + j * 16 + r16) * 32 + kq);
#pragma unroll
        for (int i = 0; i < 4; i++)
#pragma unroll
            for (int j = 0; j < 4; j++)
                acc[i][j] = __builtin_amdgcn_mfma_f32_16x16x32_bf16(af[i], bfr[j], acc[i][j], 0, 0, 0);
    }
#pragma unroll
    for (int i = 0; i < 4; i++)
#pragma unroll
        for (int j = 0; j < 4; j++) {
            int row = bm + wm + i * 16 + quad * 4;
            int col = bn + wn + j * 16 + r16;
#pragma unroll
            for (int r = 0; r < 4; r++)
                store_val(C + (size_t)(row + r) * N + col, acc[i][j][r]);
        }
}

// ---------------- RoPE on Q,K, vectorized x8 (Q pre-scaled by SMSCALE) ----------------
__global__ void rope_qk_kernel(const bf16* __restrict__ qkv, const float* __restrict__ fc,
                               bf16* __restrict__ qr, bf16* __restrict__ kr) {
    const int row = blockIdx.y;
    const int s = row & (SEQ - 1);
    const int col = (blockIdx.x * 64 + threadIdx.x) * 8;  // 0..2552, step 8
    const bf16* src = qkv + (size_t)row * QKVD + col;
    short8 v = *(const short8*)src;
    const int j0 = (col & 63) >> 1;
    const float4* fcp = (const float4*)(fc + ((size_t)s * 32 + j0) * 2);
    float4 f01 = fcp[0];
    float4 f23 = fcp[1];

    bf16* dst;
    float sc;
    if (col < DIM) { dst = qr + (size_t)row * DIM + col; sc = SMSCALE; }
    else           { dst = kr + (size_t)row * KVD + (col - DIM); sc = 1.0f; }

    float x0 = b2f(v[0]), x1 = b2f(v[1]), x2 = b2f(v[2]), x3 = b2f(v[3]);
    float x4 = b2f(v[4]), x5 = b2f(v[5]), x6 = b2f(v[6]), x7 = b2f(v[7]);
    float c0 = f01.x * sc, s0 = f01.y * sc, c1 = f01.z * sc, s1 = f01.w * sc;
    float c2 = f23.x * sc, s2 = f23.y * sc, c3 = f23.z * sc, s3 = f23.w * sc;

    uint4 o;
    o.x = pkbf16(x0 * c0 - x1 * s0, x1 * c0 + x0 * s0);
    o.y = pkbf16(x2 * c1 - x3 * s1, x3 * c1 + x2 * s1);
    o.z = pkbf16(x4 * c2 - x5 * s2, x5 * c2 + x4 * s2);
    o.w = pkbf16(x6 * c3 - x7 * s3, x7 * c3 + x6 * s3);
    *(uint4*)dst = o;
}

// ---------------- V transpose: qkv[s][2560+kvh*64+d] -> vt[(b,kvh,d)][s] ----------------
__global__ void rope_v_kernel(const bf16* __restrict__ qkv, bf16* __restrict__ vt) {
    const int t = threadIdx.x;
    const int so = t & 63;
    const int dq = t >> 6;
    const int bk = blockIdx.y;
    const int s = blockIdx.x * 64 + so;
    const int b = bk >> 3;
    const bf16* src = qkv + ((size_t)b * SEQ + s) * QKVD + DIM + KVD + (bk & 7) * HD + dq * 16;
    short8 v0 = *(const short8*)src;
    short8 v1 = *(const short8*)(src + 8);
    short* dst = (short*)(vt + ((size_t)bk * HD + dq * 16) * SEQ + s);
#pragma unroll
    for (int j = 0; j < 8; j++) dst[(size_t)j * SEQ] = v0[j];
#pragma unroll
    for (int j = 0; j < 8; j++) dst[(size_t)(8 + j) * SEQ] = v1[j];
}

// ---------------- Flash attention: 32 q-rows per block-iter ----------------
// Each block: 4 waves = 4 q-heads (GQA), TWO 16-row sub-tiles (A: q0+r16,
// B: q0+16+r16) per staged K/V buffer. K fragments (kf) and V fragments (vf)
// are read from LDS ONCE and feed both sub-tiles -> K/V LDS staging, LDS
// reads, barriers and bank conflicts all halve per q-row vs the 16-row
// version (33.8K -> 16.9K block-iters grid-wide); MFMA/exp totals unchanged.
// Complementary pairing (qt, 63-qt) -> every block exactly 33 iters (flat).
// 512 blocks = exactly 2/CU resident; launch_bounds(256,2) -> 256-VGPR
// budget so both sub-tile states + all 16 V fragments stay live.
__global__ __launch_bounds__(256, 2) void attn_kernel(const bf16* __restrict__ qr,
                                                      const bf16* __restrict__ kr,
                                                      const bf16* __restrict__ vt,
                                                      bf16* __restrict__ out) {
    __shared__ bf16 Ks[8192];  // [buf 2][dchunk 8][key 64][8]
    __shared__ bf16 Vs[8192];  // [buf 2][kchunk 8][d 64][8]
    const int t = threadIdx.x;
    const int lane = t & 63;
    const int wv = t >> 6;
    const int quad = lane >> 4;
    const int r16 = lane & 15;

    const int wg = blockIdx.x;          // 0..511
    const int xcd = wg & 7;
    const int kk = wg >> 3;             // 0..63
    const int bk = xcd * 2 + (kk & 1);  // b*8+kvh: 2 kv-groups per XCD (L2-resident)
    const int pairIdx = kk >> 1;        // 0..31
    const int b = bk >> 3;
    const int kvh = bk & 7;
    const int h = kvh * 4 + wv;

    const bf16* Kg = kr + ((size_t)b * SEQ + lane) * KVD + kvh * HD + wv * 8;
    const bf16* Vg = vt + ((size_t)(b * NKV + kvh) * HD + lane) * SEQ + wv * 8;

    const char* kl = (const char*)Ks + quad * 1024 + r16 * 16;
    const char* vl = (const char*)Vs + (quad >> 1) * 1024 + r16 * 16 + (quad & 1) * 8;

    union PB { short4v s; unsigned u[2]; };
    const short one_bf16 = (short)0x3F80;
    const short4v ones = {one_bf16, one_bf16, one_bf16, one_bf16};

#pragma unroll 1
    for (int seg = 0; seg < 2; seg++) {
        const int qt = seg ? (63 - pairIdx) : pairIdx;   // 32-row tile index
        const int q0 = qt * 32;
        const int nkb = (qt >> 1) + 1;                   // keys 0..q0+31 -> ceil/64

        // Q fragments for both 16-row sub-tiles (B-operand), pre-scaled by SMSCALE
        const bf16* QpA = qr + ((size_t)b * SEQ + q0 + r16) * DIM + h * HD + quad * 8;
        const bf16* QpB = QpA + (size_t)16 * DIM;
        short8 qaA0 = *(const short8*)(QpA);
        short8 qaA1 = *(const short8*)(QpA + 32);
        short8 qaB0 = *(const short8*)(QpB);
        short8 qaB1 = *(const short8*)(QpB + 32);

        f32x4 oA[4] = {}, oB[4] = {};
        f32x4 olA = {}, olB = {};

        __syncthreads();  // previous segment's LDS reads done before restaging buf0
        {
            bf16* Ksd = Ks + t * 8;
            bf16* Vsd = Vs + t * 8;
            gld_lds16(Kg, Ksd);      gld_lds16(Kg + 32, Ksd + 2048);
            gld_lds16(Vg, Vsd);      gld_lds16(Vg + 32, Vsd + 2048);
        }

        for (int kb = 0; kb < nkb; kb++) {
            __syncthreads();
            const int buf = kb & 1;
            if (kb + 1 < nkb) {
                const bf16* Kgn = Kg + (size_t)(kb + 1) * 64 * KVD;
                const bf16* Vgn = Vg + (kb + 1) * 64;
                bf16* Ksd = Ks + (buf ^ 1) * 4096 + t * 8;
                bf16* Vsd = Vs + (buf ^ 1) * 4096 + t * 8;
                gld_lds16(Kgn, Ksd);      gld_lds16(Kgn + 32, Ksd + 2048);
                gld_lds16(Vgn, Vsd);      gld_lds16(Vgn + 32, Vsd + 2048);
            }
            const char* klb = kl + buf * 8192;
            const char* vlb = vl + buf * 8192;

            // S^T = K * Q^T for both sub-tiles; kf fragments read once, used twice
            const f32x4 z = {0.f, 0.f, 0.f, 0.f};
            f32x4 stA[4], stB[4];
            __builtin_amdgcn_s_setprio(1);
#pragma unroll
            for (int n = 0; n < 4; n++) {
                short8 kf0 = *(const short8*)(klb + n * 256);
                short8 kf1 = *(const short8*)(klb + 4096 + n * 256);
                stA[n] = __builtin_amdgcn_mfma_f32_16x16x32_bf16(kf0, qaA0, z, 0, 0, 0);
                stA[n] = __builtin_amdgcn_mfma_f32_16x16x32_bf16(kf1, qaA1, stA[n], 0, 0, 0);
                stB[n] = __builtin_amdgcn_mfma_f32_16x16x32_bf16(kf0, qaB0, z, 0, 0, 0);
                stB[n] = __builtin_amdgcn_mfma_f32_16x16x32_bf16(kf1, qaB1, stB[n], 0, 0, 0);
            }
            __builtin_amdgcn_s_setprio(0);

            // V fragments: read once, shared by both sub-tiles' PV
            short4v vf[4][4];
#pragma unroll
            for (int dt = 0; dt < 4; dt++)
#pragma unroll
                for (int n = 0; n < 4; n++)
                    vf[dt][n] = *(const short4v*)(vlb + n * 2048 + dt * 256);
            __builtin_amdgcn_sched_barrier(0);

            if (kb == nkb - 1) {  // diagonal block: causal mask in place
                const int kbase = kb * 64;
#pragma unroll
                for (int n = 0; n < 4; n++)
#pragma unroll
                    for (int r = 0; r < 4; r++) {
                        int key = kbase + n * 16 + quad * 4 + r;
                        if (key > q0 + r16) stA[n][r] = -__builtin_inff();
                        if (key > q0 + 16 + r16) stB[n][r] = -__builtin_inff();
                    }
            }

            // p = exp2(s) (no max, no rescale; masked keys -> 0)
            PB pbsA[4], pbsB[4];
#pragma unroll
            for (int n = 0; n < 4; n++) {
                float a0 = exp2f(stA[n][0]), a1 = exp2f(stA[n][1]);
                float a2 = exp2f(stA[n][2]), a3 = exp2f(stA[n][3]);
                pbsA[n].u[0] = pkbf16(a0, a1);
                pbsA[n].u[1] = pkbf16(a2, a3);
                float b0 = exp2f(stB[n][0]), b1 = exp2f(stB[n][1]);
                float b2 = exp2f(stB[n][2]), b3 = exp2f(stB[n][3]);
                pbsB[n].u[0] = pkbf16(b0, b1);
                pbsB[n].u[1] = pkbf16(b2, b3);
            }

            // O^T += V^T * P^T (both tiles); denominators via ones-MFMA
            __builtin_amdgcn_s_setprio(1);
#pragma unroll
            for (int dt = 0; dt < 4; dt++)
#pragma unroll
                for (int n = 0; n < 4; n++) {
                    oA[dt] = __builtin_amdgcn_mfma_f32_16x16x16bf16_1k(vf[dt][n], pbsA[n].s, oA[dt], 0, 0, 0);
                    oB[dt] = __builtin_amdgcn_mfma_f32_16x16x16bf16_1k(vf[dt][n], pbsB[n].s, oB[dt], 0, 0, 0);
                }
#pragma unroll
            for (int n = 0; n < 4; n++) {
                olA = __builtin_amdgcn_mfma_f32_16x16x16bf16_1k(ones, pbsA[n].s, olA, 0, 0, 0);
                olB = __builtin_amdgcn_mfma_f32_16x16x16bf16_1k(ones, pbsB[n].s, olB, 0, 0, 0);
            }
            __builtin_amdgcn_s_setprio(0);
        }

        // epilogue: ol[r] identical across r and quads -> no reduction needed
        float invA = 1.f / olA[0];
        float invB = 1.f / olB[0];
        bf16* OpA = out + ((size_t)b * SEQ + q0 + r16) * DIM + h * HD + quad * 4;
        bf16* OpB = OpA + (size_t)16 * DIM;
#pragma unroll
        for (int dt = 0; dt < 4; dt++) {
            PB pka, pkb;
            pka.u[0] = pkbf16(oA[dt][0] * invA, oA[dt][1] * invA);
            pka.u[1] = pkbf16(oA[dt][2] * invA, oA[dt][3] * invA);
            *(short4v*)(OpA + dt * 16) = pka.s;
            pkb.u[0] = pkbf16(oB[dt][0] * invB, oB[dt][1] * invB);
            pkb.u[1] = pkbf16(oB[dt][2] * invB, oB[dt][3] * invB);
            *(short4v*)(OpB + dt * 16) = pkb.s;
        }
    }
}

extern "C" void kernel_launch(void* const* d_in, const int* in_sizes, int n_in,
                              void* d_out, int out_size, void* d_ws, size_t ws_size,
                              hipStream_t stream) {
    (void)in_sizes; (void)n_in; (void)out_size; (void)ws_size;
    const float* x    = (const float*)d_in[0];
    const float* fc   = (const float*)d_in[1];
    const float* wqkv = (const float*)d_in[3];
    const float* wo   = (const float*)d_in[4];
    float* out = (float*)d_out;

    char* w = (char*)d_ws;
    bf16* xb    = (bf16*)(w);
    bf16* wqkvb = (bf16*)(w + 16777216);
    bf16* wob   = (bf16*)(w + 29360128);
    bf16* qkvb  = (bf16*)(w + 37748736);
    bf16* kr    = (bf16*)(w + 62914560);
    bf16* vt    = (bf16*)(w + 67108864);
    bf16* qr = xb;
    bf16* attnb = qkvb;

    cvt3_kernel<<<18432, 256, 0, stream>>>(x, wqkv, wo, xb);
    gemm_nt<bf16><<<dim3(24, 32), 256, 0, stream>>>(xb, wqkvb, qkvb, 4096, QKVD, DIM);
    rope_qk_kernel<<<dim3(5, 4096), 64, 0, stream>>>(qkvb, fc, qr, kr);
    rope_v_kernel<<<dim3(32, 16), 256, 0, stream>>>(qkvb, vt);
    attn_kernel<<<dim3(512), 256, 0, stream>>>(qr, kr, vt, attnb);
    gemm_nt<float><<<dim3(16, 32), 256, 0, stream>>>(attnb, wob, out, 4096, DIM, DIM);
}